// Round 8
// baseline (81.029 us; speedup 1.0000x reference)
//
#include <hip/hip_runtime.h>
#include <cstddef>

#define BB 64
#define MM 5
#define NN 1000
#define DD 128
#define HH 8
#define KSZ 16
#define NCH 8        // k2 chunks per b (all-h blocks)
#define CH2 125      // k2 chunk size
#define NC3 16       // k3 chunks per b
#define CH3 63       // k3 chunk size (16*63=1008 >= 1000, guarded)
#define INV_SQRT_D 0.08838834764831845f

__device__ __forceinline__ float tanh_fast(float x) {
  float e = __expf(2.f * x);
  return 1.f - 2.f / (e + 1.f);   // safe at +/-inf
}

// ---------------- k1: blocks [0,256): (b, d-quarter) query projection.
// Each block computes q for d in [dq*32, dq*32+32) for all 5 m, and qw for
// its two heads h = 2dq, 2dq+1. wpcv traffic per block = 17KB (was 67KB).
// Blocks [256,320): pack feasibility mask bits -> pmask[b][n].
__global__ __launch_bounds__(256) void k1_query(
    const float* __restrict__ fc, const float* __restrict__ pne,
    const float* __restrict__ vdf, const float* __restrict__ wpcv,
    const float* __restrict__ wpns, const int* __restrict__ mask,
    float* __restrict__ q_ws, float* __restrict__ qw_ws,
    unsigned int* __restrict__ pmask)
{
  const int t = threadIdx.x;
  if (blockIdx.x >= BB * 4) {          // mask-pack blocks
    const int b = blockIdx.x - BB * 4;
    const int* mb = mask + (size_t)(b * MM) * NN;
    for (int n = t; n < NN; n += 256) {
      unsigned int pm = 0;
#pragma unroll
      for (int m = 0; m < MM; ++m) pm |= (mb[m * NN + n] != 0 ? 1u : 0u) << m;
      pmask[b * NN + n] = pm;
    }
    return;
  }
  const int b = blockIdx.x >> 2;
  const int dq = blockIdx.x & 3;
  const int k = t & 15, gid = t >> 4;  // 16 groups of 16 lanes
  __shared__ float qsh[MM][32];

  float cvr[9];
  int curm = -1;
  for (int r = 0; r < 10; ++r) {       // r = m*2 + dhalf
    const int m = r >> 1;
    if (m != curm) {
      curm = m;
      const float* pner = pne + (size_t)(b * MM + m) * DD;
#pragma unroll
      for (int jp = 0; jp < 8; ++jp) cvr[jp] = pner[k + 16 * jp];
      cvr[8] = (k < 3) ? vdf[(b * MM + m) * 3 + k] : 0.f;
    }
    const int dl = (r & 1) * 16 + gid;
    const int d = dq * 32 + dl;
    const float* wrow = wpcv + d * 131;
    float p = 0.f;
#pragma unroll
    for (int jp = 0; jp < 8; ++jp) p = fmaf(cvr[jp], wrow[k + 16 * jp], p);
    if (k < 3) p = fmaf(cvr[8], wrow[128 + k], p);
    p += __shfl_xor(p, 1); p += __shfl_xor(p, 2);
    p += __shfl_xor(p, 4); p += __shfl_xor(p, 8);
    if (k == 0) {
      const float q = 0.25f * (p + fc[b * DD + d]);   // fold 1/sqrt(KS)
      qsh[m][dl] = q;
      q_ws[(size_t)(b * MM + m) * DD + d] = q;
    }
  }
  __syncthreads();
  if (t < 80) {
    const int hh = t / 40;             // 0/1 within this quarter
    const int r = t - hh * 40, m = r >> 3, f = r & 7;
    const int h = dq * 2 + hh;
    float acc = 0.f;
#pragma unroll
    for (int kk = 0; kk < KSZ; ++kk)
      acc = fmaf(qsh[m][hh * 16 + kk], wpns[(DD + h * KSZ + kk) * 8 + f], acc);
    qw_ws[(b * HH + h) * 40 + m * 8 + f] = acc;
  }
}

// ---------------- k2: per (b,chunk) ALL-HEAD attention partials.
// 512 thr: lane = (k in [0,4)) x (h in [0,8)) x (slot s in [0,16)).
// ndf + pmask staged once in LDS (was re-fetched by 8 per-h blocks).
// part[(b*8+c)*8+h][m*16+kk] = sum_n e*V ; [80+m*8+f] = sum_n e*ndf ; [120] = sum e.
__global__ __launch_bounds__(512, 4) void k2_attn(
    const float* __restrict__ ndf, const float* __restrict__ gV,
    const float* __restrict__ gK, const unsigned int* __restrict__ pmask,
    const float* __restrict__ q_ws, const float* __restrict__ qw_ws,
    float* __restrict__ part)
{
  const int b = blockIdx.x & 63;       // XCD-affinity: all chunks of b on one XCD
  const int c = blockIdx.x >> 6;
  const int t = threadIdx.x;
  const int k = t & 3;
  const int h = (t >> 2) & 7;
  const int s = t >> 5;                // 16 n-slots
  const int n0 = c * CH2;

  __shared__ float nlds[CH2][MM][8];   // 20000 B, [n][m][f]
  __shared__ unsigned int pmlds[CH2];
  __shared__ float pP[HH][128];        // 4 KB accumulator

  // stage ndf (float4), pmask; zero pP
  for (int i = t; i < CH2 * MM * 2; i += 512) {    // 1250 float4
    const int m = i / 250;
    const int r = i - m * 250;
    const int n = r >> 1, jj = r & 1;
    const float4 v = *(const float4*)(ndf + ((size_t)(b * MM + m) * NN + n0 + n) * 8 + 4 * jj);
    *(float4*)(&nlds[n][m][4 * jj]) = v;
  }
  for (int i = t; i < CH2; i += 512) pmlds[i] = pmask[b * NN + n0 + i];
  for (int i = t; i < HH * 128; i += 512) pP[i >> 7][i & 127] = 0.f;

  float4 qr[MM];
  float2 qwr[MM];
#pragma unroll
  for (int m = 0; m < MM; ++m) {
    qr[m] = *(const float4*)(q_ws + (size_t)(b * MM + m) * DD + h * KSZ + 4 * k);
    qwr[m] = *(const float2*)(qw_ws + (b * HH + h) * 40 + m * 8 + 2 * k);
  }
  __syncthreads();

  const float* kb = gK + ((size_t)(h * BB + b) * NN + n0) * KSZ + 4 * k;
  const float* vb = gV + ((size_t)(h * BB + b) * NN + n0) * KSZ + 4 * k;

  float4 hacc[MM] = {};
  float2 afv[MM] = {};
  float lsum = 0.f;

#pragma unroll
  for (int i = 0; i < 8; ++i) {
    const int nl = s + 16 * i;
    if (nl < CH2) {                    // only body 7 is conditional
      const float4 kv = *(const float4*)(kb + nl * KSZ);
      const float4 vv = *(const float4*)(vb + nl * KSZ);
      const unsigned int pm = pmlds[nl];
#pragma unroll
      for (int m = 0; m < MM; ++m) {
        const float2 nd = *(const float2*)(&nlds[nl][m][2 * k]);
        float p = kv.x * qr[m].x + kv.y * qr[m].y
                + kv.z * qr[m].z + kv.w * qr[m].w
                + nd.x * qwr[m].x + nd.y * qwr[m].y;
        p += __shfl_xor(p, 1); p += __shfl_xor(p, 2);
        const float e = ((pm >> m) & 1u) ? __expf(p) : 0.f;
        hacc[m].x = fmaf(e, vv.x, hacc[m].x);
        hacc[m].y = fmaf(e, vv.y, hacc[m].y);
        hacc[m].z = fmaf(e, vv.z, hacc[m].z);
        hacc[m].w = fmaf(e, vv.w, hacc[m].w);
        afv[m].x = fmaf(e, nd.x, afv[m].x);
        afv[m].y = fmaf(e, nd.y, afv[m].y);
        lsum += e;
      }
    }
  }

  // fold the wave's two s-slots, then LDS-atomic accumulate (8 waves)
#pragma unroll
  for (int m = 0; m < MM; ++m) {
    hacc[m].x += __shfl_xor(hacc[m].x, 32);
    hacc[m].y += __shfl_xor(hacc[m].y, 32);
    hacc[m].z += __shfl_xor(hacc[m].z, 32);
    hacc[m].w += __shfl_xor(hacc[m].w, 32);
    afv[m].x += __shfl_xor(afv[m].x, 32);
    afv[m].y += __shfl_xor(afv[m].y, 32);
  }
  lsum += __shfl_xor(lsum, 32);

  if ((t & 63) < 32) {
#pragma unroll
    for (int m = 0; m < MM; ++m) {
      atomicAdd(&pP[h][m * 16 + 4 * k + 0], hacc[m].x);
      atomicAdd(&pP[h][m * 16 + 4 * k + 1], hacc[m].y);
      atomicAdd(&pP[h][m * 16 + 4 * k + 2], hacc[m].z);
      atomicAdd(&pP[h][m * 16 + 4 * k + 3], hacc[m].w);
      atomicAdd(&pP[h][80 + m * 8 + 2 * k + 0], afv[m].x);
      atomicAdd(&pP[h][80 + m * 8 + 2 * k + 1], afv[m].y);
    }
    if (k == 0) atomicAdd(&pP[h][120], lsum);
  }
  __syncthreads();
  float* P = part + (size_t)(b * NCH + c) * HH * 128;
  for (int i = t; i < HH * 128; i += 512) P[i] = pP[i >> 7][i & 127];
}

// ---------------- k2b: per-b combine chunks -> conc -> fq (prescaled), fw
__global__ __launch_bounds__(256) void k2b_combine(
    const float* __restrict__ part, const float* __restrict__ wpns,
    const float* __restrict__ po, float* __restrict__ fq_ws,
    float* __restrict__ fw_ws)
{
  const int b = blockIdx.x;
  const int t = threadIdx.x;
  __shared__ float pos[DD][129];   // stride 129: conflict-free column reads
  __shared__ float rgs[HH];
  __shared__ float afs[HH][MM][8];
  __shared__ float cs[MM][DD];
  __shared__ float fqs[MM][DD];

  for (int i = t; i < DD * DD / 4; i += 256) {
    const float4 v = ((const float4*)po)[i];
    const int r = (i * 4) >> 7, cc = (i * 4) & 127;
    pos[r][cc] = v.x; pos[r][cc + 1] = v.y; pos[r][cc + 2] = v.z; pos[r][cc + 3] = v.w;
  }
  const float* pb = part + (size_t)b * NCH * HH * 128;
  if (t < HH) {
    float s = 0.f;
#pragma unroll
    for (int c = 0; c < NCH; ++c) s += pb[(c * HH + t) * 128 + 120];
    rgs[t] = 1.f / s;
  }
  // FIX R7: HH*MM*8 = 320 > 256 threads — must be a strided loop, not `if`.
  for (int idx = t; idx < HH * MM * 8; idx += 256) {
    const int h = idx / 40, r = idx % 40;
    float a = 0.f;
#pragma unroll
    for (int c = 0; c < NCH; ++c) a += pb[(c * HH + h) * 128 + 80 + r];
    afs[h][r >> 3][r & 7] = a;
  }
  __syncthreads();
  for (int idx = t; idx < MM * DD; idx += 256) {
    const int m = idx >> 7, d = idx & 127, h = d >> 4;
    float a = 0.f;
#pragma unroll
    for (int c = 0; c < NCH; ++c) a += pb[(c * HH + h) * 128 + m * 16 + (d & 15)];
    float cf = 0.f;
#pragma unroll
    for (int f = 0; f < 8; ++f) cf = fmaf(wpns[d * 8 + f], afs[h][m][f], cf);
    cs[m][d] = (a + cf) * rgs[h];
  }
  __syncthreads();
  for (int idx = t; idx < MM * DD; idx += 256) {
    const int m = idx >> 7, d = idx & 127;
    float acc = 0.f;
#pragma unroll 8
    for (int j = 0; j < DD; ++j) acc = fmaf(cs[m][j], pos[d][j], acc);
    acc *= INV_SQRT_D;   // fold 1/sqrt(D)
    fqs[m][d] = acc;
    fq_ws[(size_t)b * (MM * DD) + idx] = acc;
  }
  __syncthreads();
  if (t < MM * 8) {
    const int m = t >> 3, f = t & 7;
    float acc = 0.f;
#pragma unroll 16
    for (int d = 0; d < DD; ++d) acc = fmaf(fqs[m][d], wpns[(2 * DD + d) * 8 + f], acc);
    fw_ws[b * 40 + t] = acc;
  }
}

// ---------------- k3: per (b,chunk) logits via 16-lane shfl-dot, direct exp.
// NC3=16 chunks (1024 blocks, 256 thr). Writes e-values to out, sums to stats.
__global__ __launch_bounds__(256) void k3_logits(
    const float* __restrict__ ndf, const float* __restrict__ lK,
    const unsigned int* __restrict__ pmask, const float* __restrict__ fq_ws,
    const float* __restrict__ fw_ws, float* __restrict__ out,
    float* __restrict__ stats)
{
  const int b = blockIdx.x & 63;       // XCD-affinity for per-b shared data
  const int c = blockIdx.x >> 6;
  const int t = threadIdx.x;
  const int k = t & 15, gid = t >> 4;  // 16 groups of 16 lanes
  const int n0 = c * CH3;

  float4 fqr[MM][2];
  float fwr[MM];
#pragma unroll
  for (int m = 0; m < MM; ++m) {
    fqr[m][0] = *(const float4*)(fq_ws + (size_t)(b * MM + m) * DD + 8 * k);
    fqr[m][1] = *(const float4*)(fq_ws + (size_t)(b * MM + m) * DD + 8 * k + 4);
    fwr[m] = fw_ws[b * 40 + m * 8 + (k & 7)];
  }
  float lsum = 0.f;

#pragma unroll
  for (int i = 0; i < 4; ++i) {
    const int nl = gid + 16 * i;
    const int n = n0 + nl;
    const bool valid = (nl < CH3) && (n < NN);   // group-uniform
    const int nc = valid ? n : n0;
    const unsigned int pm = valid ? pmask[b * NN + nc] : 0u;
    const float* lkr = lK + ((size_t)b * NN + nc) * DD;
    const float4 l0 = *(const float4*)(lkr + 8 * k);
    const float4 l1 = *(const float4*)(lkr + 8 * k + 4);
    float ndv[MM];
#pragma unroll
    for (int m = 0; m < MM; ++m)
      ndv[m] = (k < 8) ? ndf[((size_t)(b * MM + m) * NN + nc) * 8 + k] : 0.f;
#pragma unroll
    for (int m = 0; m < MM; ++m) {
      float p = l0.x * fqr[m][0].x + l0.y * fqr[m][0].y
              + l0.z * fqr[m][0].z + l0.w * fqr[m][0].w
              + l1.x * fqr[m][1].x + l1.y * fqr[m][1].y
              + l1.z * fqr[m][1].z + l1.w * fqr[m][1].w
              + ndv[m] * fwr[m];
      p += __shfl_xor(p, 1); p += __shfl_xor(p, 2);
      p += __shfl_xor(p, 4); p += __shfl_xor(p, 8);
      const float e = ((pm >> m) & 1u) ? __expf(tanh_fast(p) * 10.f) : 0.f;
      if (valid) {
        lsum += e;
        if (k == 0) out[(size_t)(b * MM + m) * NN + nc] = e;
      }
    }
  }
  // per-lane lsum already holds its group's sum; xor16/32 sums the 4 groups.
  lsum += __shfl_xor(lsum, 16);
  lsum += __shfl_xor(lsum, 32);
  __shared__ float wred[4];
  if ((t & 63) == 0) wred[t >> 6] = lsum;
  __syncthreads();
  if (t == 0)
    stats[b * NC3 + c] = wred[0] + wred[1] + wred[2] + wred[3];
}

// ---------------- k4: per (b,m) scale row by 1/sum
__global__ __launch_bounds__(256) void k4_probs(
    const float* __restrict__ stats, float* __restrict__ out)
{
  const int bm = blockIdx.x;
  const int b = bm / MM;
  const int t = threadIdx.x;
  float s = 0.f;
#pragma unroll
  for (int c = 0; c < NC3; ++c) s += stats[b * NC3 + c];
  const float scale = 1.f / s;
  if (t < 250) {
    float4* p = (float4*)(out + (size_t)bm * NN);
    float4 v = p[t];
    v.x *= scale; v.y *= scale; v.z *= scale; v.w *= scale;
    p[t] = v;
  }
}

extern "C" void kernel_launch(void* const* d_in, const int* in_sizes, int n_in,
                              void* d_out, int out_size, void* d_ws, size_t ws_size,
                              hipStream_t stream) {
  // d_in[0] = node_embeddings: dead input, never read.
  const float* fc   = (const float*)d_in[1];
  const float* pne  = (const float*)d_in[2];
  const float* ndf  = (const float*)d_in[3];
  const float* vdf  = (const float*)d_in[4];
  const float* gV   = (const float*)d_in[5];
  const float* gK   = (const float*)d_in[6];
  const float* lK   = (const float*)d_in[7];
  const int*   mask = (const int*)d_in[8];
  const float* wpcv = (const float*)d_in[9];
  const float* wpns = (const float*)d_in[10];
  const float* po   = (const float*)d_in[11];

  float* q_ws  = (float*)d_ws;                        // 40960
  float* qw_ws = q_ws + BB * MM * DD;                 // 20480
  float* part  = qw_ws + BB * HH * 40;                // 64*8*8*128 = 524288
  float* fq_ws = part + (size_t)BB * NCH * HH * 128;  // 40960
  float* fw_ws = fq_ws + BB * MM * DD;                // 2560
  float* stats = fw_ws + BB * 40;                     // 1024
  unsigned int* pmask = (unsigned int*)(stats + BB * NC3);  // 64000 u32
  float* out   = (float*)d_out;

  k1_query<<<BB * 4 + BB, 256, 0, stream>>>(fc, pne, vdf, wpcv, wpns, mask,
                                            q_ws, qw_ws, pmask);
  k2_attn<<<BB * NCH, 512, 0, stream>>>(ndf, gV, gK, pmask, q_ws, qw_ws, part);
  k2b_combine<<<BB, 256, 0, stream>>>(part, wpns, po, fq_ws, fw_ws);
  k3_logits<<<BB * NC3, 256, 0, stream>>>(ndf, lK, pmask, fq_ws, fw_ws, out, stats);
  k4_probs<<<BB * MM, 256, 0, stream>>>(stats, out);
}

// Round 9
// 69.028 us; speedup vs baseline: 1.1739x; 1.1739x over previous
//
#include <hip/hip_runtime.h>
#include <cstddef>

#define BB 64
#define MM 5
#define NN 1000
#define DD 128
#define HH 8
#define KSZ 16
#define NCH 8        // k2 chunks per (b,h)
#define CH2 125      // k2 chunk size
#define NC3 16       // k3 chunks per b
#define CH3 63       // k3 chunk size (16*63=1008 >= 1000, guarded)
#define INV_SQRT_D 0.08838834764831845f

__device__ __forceinline__ float tanh_fast(float x) {
  float e = __expf(2.f * x);
  return 1.f - 2.f / (e + 1.f);   // safe at +/-inf
}

// ---------------- k1: blocks [0,256): (b, d-quarter) query projection.
// Blocks [256,320): pack feasibility mask bits -> pmask[b][n].
__global__ __launch_bounds__(256) void k1_query(
    const float* __restrict__ fc, const float* __restrict__ pne,
    const float* __restrict__ vdf, const float* __restrict__ wpcv,
    const float* __restrict__ wpns, const int* __restrict__ mask,
    float* __restrict__ q_ws, float* __restrict__ qw_ws,
    unsigned int* __restrict__ pmask)
{
  const int t = threadIdx.x;
  if (blockIdx.x >= BB * 4) {          // mask-pack blocks
    const int b = blockIdx.x - BB * 4;
    const int* mb = mask + (size_t)(b * MM) * NN;
    for (int n = t; n < NN; n += 256) {
      unsigned int pm = 0;
#pragma unroll
      for (int m = 0; m < MM; ++m) pm |= (mb[m * NN + n] != 0 ? 1u : 0u) << m;
      pmask[b * NN + n] = pm;
    }
    return;
  }
  const int b = blockIdx.x >> 2;
  const int dq = blockIdx.x & 3;
  const int k = t & 15, gid = t >> 4;  // 16 groups of 16 lanes
  __shared__ float qsh[MM][32];

  float cvr[9];
  int curm = -1;
  for (int r = 0; r < 10; ++r) {       // r = m*2 + dhalf
    const int m = r >> 1;
    if (m != curm) {
      curm = m;
      const float* pner = pne + (size_t)(b * MM + m) * DD;
#pragma unroll
      for (int jp = 0; jp < 8; ++jp) cvr[jp] = pner[k + 16 * jp];
      cvr[8] = (k < 3) ? vdf[(b * MM + m) * 3 + k] : 0.f;
    }
    const int dl = (r & 1) * 16 + gid;
    const int d = dq * 32 + dl;
    const float* wrow = wpcv + d * 131;
    float p = 0.f;
#pragma unroll
    for (int jp = 0; jp < 8; ++jp) p = fmaf(cvr[jp], wrow[k + 16 * jp], p);
    if (k < 3) p = fmaf(cvr[8], wrow[128 + k], p);
    p += __shfl_xor(p, 1); p += __shfl_xor(p, 2);
    p += __shfl_xor(p, 4); p += __shfl_xor(p, 8);
    if (k == 0) {
      const float q = 0.25f * (p + fc[b * DD + d]);   // fold 1/sqrt(KS)
      qsh[m][dl] = q;
      q_ws[(size_t)(b * MM + m) * DD + d] = q;
    }
  }
  __syncthreads();
  if (t < 80) {
    const int hh = t / 40;             // 0/1 within this quarter
    const int r = t - hh * 40, m = r >> 3, f = r & 7;
    const int h = dq * 2 + hh;
    float acc = 0.f;
#pragma unroll
    for (int kk = 0; kk < KSZ; ++kk)
      acc = fmaf(qsh[m][hh * 16 + kk], wpns[(DD + h * KSZ + kk) * 8 + f], acc);
    qw_ws[(b * HH + h) * 40 + m * 8 + f] = acc;
  }
}

// ---------------- k2: per (b,h,chunk) attention partials. 4-lane groups,
// 2 bodies/thread, ALL global loads issued before compute (2-deep pipeline).
// XCD-affinity: blk = (b%8) + 8*((b/8)*64 + h*8 + c)  -> xcd = b%8.
// part[(b*NCH+c)*HH+h][m*16+kk]=sum e*V ; [80+m*8+f]=sum e*ndf ; [120]=sum e.
__global__ __launch_bounds__(256, 4) void k2_attn(
    const float* __restrict__ ndf, const float* __restrict__ gV,
    const float* __restrict__ gK, const unsigned int* __restrict__ pmask,
    const float* __restrict__ q_ws, const float* __restrict__ qw_ws,
    float* __restrict__ part)
{
  const int blk = blockIdx.x;
  const int xcd = blk & 7;
  const int rest = blk >> 3;           // (b/8)*64 + h*8 + c
  const int c = rest & 7;
  const int h = (rest >> 3) & 7;
  const int b = (rest >> 6) * 8 + xcd;
  const int t = threadIdx.x;
  const int k = t & 3, gid = t >> 2;   // 64 groups of 4 lanes
  const int n0 = c * CH2;

  const float* kb = gK + ((size_t)(h * BB + b) * NN + n0) * KSZ + 4 * k;
  const float* vb = gV + ((size_t)(h * BB + b) * NN + n0) * KSZ + 4 * k;
  const float* nb = ndf + ((size_t)(b * MM) * NN + n0) * 8 + 2 * k;
  const unsigned int* pmb = pmask + b * NN + n0;

  // ---- issue ALL body loads up-front
  const int n1 = gid;                        // < 125 always
  const bool v2 = (gid < CH2 - 64);          // gid < 61
  const int n2 = v2 ? gid + 64 : 0;
  const unsigned int pm1 = pmb[n1];
  const unsigned int pm2 = v2 ? pmb[n2] : 0u;
  const float4 kv1 = *(const float4*)(kb + n1 * KSZ);
  const float4 kv2 = *(const float4*)(kb + n2 * KSZ);
  const float4 vv1 = *(const float4*)(vb + n1 * KSZ);
  const float4 vv2 = *(const float4*)(vb + n2 * KSZ);
  float2 nd1[MM], nd2[MM];
#pragma unroll
  for (int m = 0; m < MM; ++m) {
    nd1[m] = *(const float2*)(nb + ((size_t)m * NN + n1) * 8);
    nd2[m] = *(const float2*)(nb + ((size_t)m * NN + n2) * 8);
  }

  float4 qr[MM];
  float2 qwr[MM];
#pragma unroll
  for (int m = 0; m < MM; ++m) {
    qr[m] = *(const float4*)(q_ws + (size_t)(b * MM + m) * DD + h * KSZ + 4 * k);
    qwr[m] = *(const float2*)(qw_ws + (b * HH + h) * 40 + m * 8 + 2 * k);
  }

  float4 hacc[MM] = {};
  float2 afv[MM] = {};
  float lsum = 0.f;

#pragma unroll
  for (int m = 0; m < MM; ++m) {
    float p = kv1.x * qr[m].x + kv1.y * qr[m].y
            + kv1.z * qr[m].z + kv1.w * qr[m].w
            + nd1[m].x * qwr[m].x + nd1[m].y * qwr[m].y;
    p += __shfl_xor(p, 1); p += __shfl_xor(p, 2);
    const float e = ((pm1 >> m) & 1u) ? __expf(p) : 0.f;
    hacc[m].x = fmaf(e, vv1.x, hacc[m].x);
    hacc[m].y = fmaf(e, vv1.y, hacc[m].y);
    hacc[m].z = fmaf(e, vv1.z, hacc[m].z);
    hacc[m].w = fmaf(e, vv1.w, hacc[m].w);
    afv[m].x = fmaf(e, nd1[m].x, afv[m].x);
    afv[m].y = fmaf(e, nd1[m].y, afv[m].y);
    lsum += e;
  }
#pragma unroll
  for (int m = 0; m < MM; ++m) {
    float p = kv2.x * qr[m].x + kv2.y * qr[m].y
            + kv2.z * qr[m].z + kv2.w * qr[m].w
            + nd2[m].x * qwr[m].x + nd2[m].y * qwr[m].y;
    p += __shfl_xor(p, 1); p += __shfl_xor(p, 2);
    const float e = ((pm2 >> m) & 1u) ? __expf(p) : 0.f;
    hacc[m].x = fmaf(e, vv2.x, hacc[m].x);
    hacc[m].y = fmaf(e, vv2.y, hacc[m].y);
    hacc[m].z = fmaf(e, vv2.z, hacc[m].z);
    hacc[m].w = fmaf(e, vv2.w, hacc[m].w);
    afv[m].x = fmaf(e, nd2[m].x, afv[m].x);
    afv[m].y = fmaf(e, nd2[m].y, afv[m].y);
    lsum += e;
  }

  // reduce across the 16 groups of each wave (k-slot preserved by xor>=4)
#pragma unroll
  for (int m = 0; m < MM; ++m) {
#pragma unroll
    for (int off = 4; off <= 32; off <<= 1) {
      hacc[m].x += __shfl_xor(hacc[m].x, off);
      hacc[m].y += __shfl_xor(hacc[m].y, off);
      hacc[m].z += __shfl_xor(hacc[m].z, off);
      hacc[m].w += __shfl_xor(hacc[m].w, off);
      afv[m].x += __shfl_xor(afv[m].x, off);
      afv[m].y += __shfl_xor(afv[m].y, off);
    }
  }
#pragma unroll
  for (int off = 4; off <= 32; off <<= 1) lsum += __shfl_xor(lsum, off);

  __shared__ float redh[4][MM][KSZ];
  __shared__ float redaf[4][MM][8];
  __shared__ float reds[4];
  const int w = t >> 6;
  if ((t & 63) < 4) {
    const int kk = t & 3;
#pragma unroll
    for (int m = 0; m < MM; ++m) {
      redh[w][m][4 * kk + 0] = hacc[m].x;
      redh[w][m][4 * kk + 1] = hacc[m].y;
      redh[w][m][4 * kk + 2] = hacc[m].z;
      redh[w][m][4 * kk + 3] = hacc[m].w;
      redaf[w][m][2 * kk + 0] = afv[m].x;
      redaf[w][m][2 * kk + 1] = afv[m].y;
    }
  }
  if ((t & 63) == 0) reds[w] = lsum;
  __syncthreads();
  float* P = part + (size_t)((b * NCH + c) * HH + h) * 128;
  if (t < 80) {
    const int m = t >> 4, kk = t & 15;
    P[t] = redh[0][m][kk] + redh[1][m][kk] + redh[2][m][kk] + redh[3][m][kk];
  } else if (t < 120) {
    const int r = t - 80, m = r >> 3, f = r & 7;
    P[80 + r] = redaf[0][m][f] + redaf[1][m][f] + redaf[2][m][f] + redaf[3][m][f];
  } else if (t == 120) {
    P[120] = reds[0] + reds[1] + reds[2] + reds[3];
  }
}

// ---------------- k2b: per-b combine chunks -> conc -> fq (prescaled), fw
__global__ __launch_bounds__(256) void k2b_combine(
    const float* __restrict__ part, const float* __restrict__ wpns,
    const float* __restrict__ po, float* __restrict__ fq_ws,
    float* __restrict__ fw_ws)
{
  const int b = blockIdx.x;
  const int t = threadIdx.x;
  __shared__ float pos[DD][129];   // stride 129: conflict-free column reads
  __shared__ float rgs[HH];
  __shared__ float afs[HH][MM][8];
  __shared__ float cs[MM][DD];
  __shared__ float fqs[MM][DD];

  for (int i = t; i < DD * DD / 4; i += 256) {
    const float4 v = ((const float4*)po)[i];
    const int r = (i * 4) >> 7, cc = (i * 4) & 127;
    pos[r][cc] = v.x; pos[r][cc + 1] = v.y; pos[r][cc + 2] = v.z; pos[r][cc + 3] = v.w;
  }
  const float* pb = part + (size_t)b * NCH * HH * 128;
  if (t < HH) {
    float s = 0.f;
#pragma unroll
    for (int c = 0; c < NCH; ++c) s += pb[(c * HH + t) * 128 + 120];
    rgs[t] = 1.f / s;
  }
  // HH*MM*8 = 320 > 256 threads — strided loop required.
  for (int idx = t; idx < HH * MM * 8; idx += 256) {
    const int h = idx / 40, r = idx % 40;
    float a = 0.f;
#pragma unroll
    for (int c = 0; c < NCH; ++c) a += pb[(c * HH + h) * 128 + 80 + r];
    afs[h][r >> 3][r & 7] = a;
  }
  __syncthreads();
  for (int idx = t; idx < MM * DD; idx += 256) {
    const int m = idx >> 7, d = idx & 127, h = d >> 4;
    float a = 0.f;
#pragma unroll
    for (int c = 0; c < NCH; ++c) a += pb[(c * HH + h) * 128 + m * 16 + (d & 15)];
    float cf = 0.f;
#pragma unroll
    for (int f = 0; f < 8; ++f) cf = fmaf(wpns[d * 8 + f], afs[h][m][f], cf);
    cs[m][d] = (a + cf) * rgs[h];
  }
  __syncthreads();
  for (int idx = t; idx < MM * DD; idx += 256) {
    const int m = idx >> 7, d = idx & 127;
    float acc = 0.f;
#pragma unroll 8
    for (int j = 0; j < DD; ++j) acc = fmaf(cs[m][j], pos[d][j], acc);
    acc *= INV_SQRT_D;   // fold 1/sqrt(D)
    fqs[m][d] = acc;
    fq_ws[(size_t)b * (MM * DD) + idx] = acc;
  }
  __syncthreads();
  if (t < MM * 8) {
    const int m = t >> 3, f = t & 7;
    float acc = 0.f;
#pragma unroll 16
    for (int d = 0; d < DD; ++d) acc = fmaf(fqs[m][d], wpns[(2 * DD + d) * 8 + f], acc);
    fw_ws[b * 40 + t] = acc;
  }
}

// ---------------- k3: per (b,chunk) logits, 16-lane shfl-dot, direct exp.
// Pairwise-hoisted loads (2 bodies in flight). NC3=16 chunks, 256 thr.
__global__ __launch_bounds__(256, 4) void k3_logits(
    const float* __restrict__ ndf, const float* __restrict__ lK,
    const unsigned int* __restrict__ pmask, const float* __restrict__ fq_ws,
    const float* __restrict__ fw_ws, float* __restrict__ out,
    float* __restrict__ stats)
{
  const int b = blockIdx.x & 63;       // XCD-affinity for per-b shared data
  const int c = blockIdx.x >> 6;
  const int t = threadIdx.x;
  const int k = t & 15, gid = t >> 4;  // 16 groups of 16 lanes
  const int n0 = c * CH3;

  float4 fqr[MM][2];
  float fwr[MM];
#pragma unroll
  for (int m = 0; m < MM; ++m) {
    fqr[m][0] = *(const float4*)(fq_ws + (size_t)(b * MM + m) * DD + 8 * k);
    fqr[m][1] = *(const float4*)(fq_ws + (size_t)(b * MM + m) * DD + 8 * k + 4);
    fwr[m] = fw_ws[b * 40 + m * 8 + (k & 7)];
  }
  float lsum = 0.f;

#pragma unroll
  for (int half = 0; half < 2; ++half) {
    float4 l0[2], l1[2];
    float ndv[2][MM];
    unsigned int pm[2];
    int ng[2];
    bool vld[2];
#pragma unroll
    for (int j = 0; j < 2; ++j) {
      const int nl = gid + 16 * (half * 2 + j);
      const int n = n0 + nl;
      vld[j] = (nl < CH3) && (n < NN);   // group-uniform
      const int nc = vld[j] ? n : n0;
      ng[j] = nc;
      pm[j] = vld[j] ? pmask[b * NN + nc] : 0u;
      const float* lkr = lK + ((size_t)b * NN + nc) * DD;
      l0[j] = *(const float4*)(lkr + 8 * k);
      l1[j] = *(const float4*)(lkr + 8 * k + 4);
#pragma unroll
      for (int m = 0; m < MM; ++m)
        ndv[j][m] = (k < 8) ? ndf[((size_t)(b * MM + m) * NN + nc) * 8 + k] : 0.f;
    }
#pragma unroll
    for (int j = 0; j < 2; ++j) {
#pragma unroll
      for (int m = 0; m < MM; ++m) {
        float p = l0[j].x * fqr[m][0].x + l0[j].y * fqr[m][0].y
                + l0[j].z * fqr[m][0].z + l0[j].w * fqr[m][0].w
                + l1[j].x * fqr[m][1].x + l1[j].y * fqr[m][1].y
                + l1[j].z * fqr[m][1].z + l1[j].w * fqr[m][1].w
                + ndv[j][m] * fwr[m];
        p += __shfl_xor(p, 1); p += __shfl_xor(p, 2);
        p += __shfl_xor(p, 4); p += __shfl_xor(p, 8);
        const float e = ((pm[j] >> m) & 1u) ? __expf(tanh_fast(p) * 10.f) : 0.f;
        if (vld[j]) {
          lsum += e;
          if (k == 0) out[(size_t)(b * MM + m) * NN + ng[j]] = e;
        }
      }
    }
  }
  // per-lane lsum already holds its group's sum; xor16/32 sums the 4 groups.
  lsum += __shfl_xor(lsum, 16);
  lsum += __shfl_xor(lsum, 32);
  __shared__ float wred[4];
  if ((t & 63) == 0) wred[t >> 6] = lsum;
  __syncthreads();
  if (t == 0)
    stats[b * NC3 + c] = wred[0] + wred[1] + wred[2] + wred[3];
}

// ---------------- k4: per (b,m) scale row by 1/sum
__global__ __launch_bounds__(256) void k4_probs(
    const float* __restrict__ stats, float* __restrict__ out)
{
  const int bm = blockIdx.x;
  const int b = bm / MM;
  const int t = threadIdx.x;
  float s = 0.f;
#pragma unroll
  for (int c = 0; c < NC3; ++c) s += stats[b * NC3 + c];
  const float scale = 1.f / s;
  if (t < 250) {
    float4* p = (float4*)(out + (size_t)bm * NN);
    float4 v = p[t];
    v.x *= scale; v.y *= scale; v.z *= scale; v.w *= scale;
    p[t] = v;
  }
}

extern "C" void kernel_launch(void* const* d_in, const int* in_sizes, int n_in,
                              void* d_out, int out_size, void* d_ws, size_t ws_size,
                              hipStream_t stream) {
  // d_in[0] = node_embeddings: dead input, never read.
  const float* fc   = (const float*)d_in[1];
  const float* pne  = (const float*)d_in[2];
  const float* ndf  = (const float*)d_in[3];
  const float* vdf  = (const float*)d_in[4];
  const float* gV   = (const float*)d_in[5];
  const float* gK   = (const float*)d_in[6];
  const float* lK   = (const float*)d_in[7];
  const int*   mask = (const int*)d_in[8];
  const float* wpcv = (const float*)d_in[9];
  const float* wpns = (const float*)d_in[10];
  const float* po   = (const float*)d_in[11];

  float* q_ws  = (float*)d_ws;                        // 40960
  float* qw_ws = q_ws + BB * MM * DD;                 // 20480
  float* part  = qw_ws + BB * HH * 40;                // 64*8*8*128 = 524288
  float* fq_ws = part + (size_t)BB * NCH * HH * 128;  // 40960
  float* fw_ws = fq_ws + BB * MM * DD;                // 2560
  float* stats = fw_ws + BB * 40;                     // 1024
  unsigned int* pmask = (unsigned int*)(stats + BB * NC3);  // 64000 u32
  float* out   = (float*)d_out;

  k1_query<<<BB * 4 + BB, 256, 0, stream>>>(fc, pne, vdf, wpcv, wpns, mask,
                                            q_ws, qw_ws, pmask);
  k2_attn<<<BB * HH * NCH, 256, 0, stream>>>(ndf, gV, gK, pmask, q_ws, qw_ws, part);
  k2b_combine<<<BB, 256, 0, stream>>>(part, wpns, po, fq_ws, fw_ws);
  k3_logits<<<BB * NC3, 256, 0, stream>>>(ndf, lK, pmask, fq_ws, fw_ws, out, stats);
  k4_probs<<<BB * MM, 256, 0, stream>>>(stats, out);
}